// Round 16
// baseline (70.281 us; speedup 1.0000x reference)
//
#include <hip/hip_runtime.h>

// RWKV-4 WKV forward. B=16, T=1024, C=2048, fp32.
// r14 structure (T-split chunked scan, 2-slot LDS ring via global_load_lds,
// one barrier/segment, counted vmcnt, raw v_exp_f32, fused prefixes) +
// WIDE y-STORES: y is staged into the consumed lk rows of the current slot
// and written as 2 nontemporal dwordx4 per wave/segment (1KB/instr granule,
// 4x fewer store requests). Refill of slot sl moves to end-of-segment
// (distance 1.8 segments ~ 7.8us >> HBM latency).
// NOTE: __builtin_nontemporal_store needs a NATIVE vector type, not HIP's
// float4 class -> use ext_vector_type(4) alias (r15 compile fix).
// vmcnt audit (per-wave FIFO; per segment: 2 nt dwordx4 stores then 4 w16
// loads at END of segment; prologue L0(4), L1(4)):
//   newer-than-L_s at top-of-segment wait:
//     s==0 (prologue): L_1 = 4
//     1<=s<=14: st_{s-1}(2) + L_{s+1}(4) = 6   [s==1: L_2(4)+st_0(2) = 6]
//     s==15: st_14(2) = 2
// Barrier audit: unchanged from r11/r14 (T/S double-buffered by s&1, one
// s_barrier per segment). y-staging hazards are intra-wave only (each wave
// stages and reads back ONLY its own 8 rows): ds_write -> lgkmcnt(0) ->
// ds_read -> lgkmcnt(0) -> refill DMA of the same rows. No extra barrier.

#define T_DIM 1024
#define CDIM  2048
#define CHUNK 8
#define WAVES 8
#define SEG   (WAVES * CHUNK)   // 64
#define NSEG  (T_DIM / SEG)     // 16
#define NEG_BIG -1e38f
#define LOG2E 1.4426950408889634f

typedef const __attribute__((address_space(1))) float* gp_t;
typedef __attribute__((address_space(3))) float* lp_t;
typedef float f32x4 __attribute__((ext_vector_type(4)));

__global__ __launch_bounds__(WAVES * 64, 4) void wkv_fwd_kernel(
    const float* __restrict__ w, const float* __restrict__ u,
    const float* __restrict__ kk, const float* __restrict__ vv,
    float* __restrict__ y)
{
    __shared__ __align__(16) float lk[2][SEG][64];   // 32 KB
    __shared__ __align__(16) float lv[2][SEG][64];   // 32 KB
    __shared__ float Tp[2][WAVES][64], Tq[2][WAVES][64], To[2][WAVES][64]; // 12 KB
    __shared__ float Sp[2][64], Sq[2][64], So[2][64];                      // 1.5 KB

    const int lane = threadIdx.x & 63;
    const int wid  = threadIdx.x >> 6;
    const int b    = blockIdx.y;
    const int c0   = blockIdx.x * 64;

    // log2-space: all log-domain quantities carry a log2(e) factor
    const float wc  = w[c0 + lane] * LOG2E;
    const float uc  = u[c0 + lane] * LOG2E;
    const float wCH = wc * (float)CHUNK;

    const size_t sbase = (size_t)b * T_DIM * CDIM + c0;  // slab base (t=0)
    const int rl = lane >> 4;           // row within 4-row group
    const int cl = (lane & 15) * 4;     // col dword
    const float* kgl = kk + sbase + (size_t)rl * CDIM + cl;
    const float* vgl = vv + sbase + (size_t)rl * CDIM + cl;
    float*       ysb = y  + sbase + (size_t)rl * CDIM + cl;  // wide-store base

    if (wid == 0) { Sp[0][lane] = 0.f; Sq[0][lane] = 0.f; So[0][lane] = NEG_BIG; }

    // issue this wave's 8 rows of one segment: 2 k-loads + 2 v-loads (w16)
    auto issue_seg = [&](int s) {
        const int sl = s & 1;
#pragma unroll
        for (int g = 0; g < 2; ++g) {
            const size_t go = (size_t)(s * SEG + wid * CHUNK + 4 * g) * CDIM;
            __builtin_amdgcn_global_load_lds((gp_t)(kgl + go),
                (lp_t)&lk[sl][wid * CHUNK + 4 * g][0], 16, 0, 0);
            __builtin_amdgcn_global_load_lds((gp_t)(vgl + go),
                (lp_t)&lv[sl][wid * CHUNK + 4 * g][0], 16, 0, 0);
        }
    };

    issue_seg(0);
    issue_seg(1);

#pragma unroll 1
    for (int s = 0; s < NSEG; ++s) {
        const int sl = s & 1;

        // wait for MY segment-s loads (exact FIFO counts, audit above)
        if (s == 0)            asm volatile("s_waitcnt vmcnt(4)" ::: "memory");
        else if (s == NSEG-1)  asm volatile("s_waitcnt vmcnt(2)" ::: "memory");
        else                   asm volatile("s_waitcnt vmcnt(6)" ::: "memory");
        __builtin_amdgcn_sched_barrier(0);

        // z-space precompute + SINGLE exclusive-prefix accumulator pass
        float uk[CHUNK], hh[CHUNK], vc[CHUNK], pP[CHUNK], pQ[CHUNK];
        float M = NEG_BIG, aP = 0.f, aQ = 0.f;
#pragma unroll
        for (int j = 0; j < CHUNK; ++j) {
            const float kt = lk[sl][wid * CHUNK + j][lane] * LOG2E;
            vc[j] = lv[sl][wid * CHUNK + j][lane];
            const float zj = fmaf((float)(-j), wc, kt);   // (k_j - j*w)*log2e
            uk[j] = uc + kt;
            const float dl = M - zj;
            const float e  = __builtin_amdgcn_exp2f(-fabsf(dl));
            const float cf = dl >= 0.f ? 1.f : e;         // carry factor
            const float df = dl >= 0.f ? e : 1.f;         // new-term factor
            hh[j] = fmaf((float)(j - 1), wc, M);          // ((j-1)w + M_j)*l2e
            M = fmaxf(M, zj);
            pP[j] = aP; pQ[j] = aQ;                       // exclusive prefixes
            aP = fmaf(cf, aP, df * vc[j]);
            aQ = fmaf(cf, aQ, df);
        }
        const float Pt = aP, Qt = aQ;                     // inclusive totals

        if (wid < WAVES - 1) {
            Tp[sl][wid][lane] = Pt; Tq[sl][wid][lane] = Qt;
            To[sl][wid][lane] = fmaf((float)(CHUNK - 1), wc, M);
        }

        // the one barrier: T(s) visible; vmem stays in flight
        asm volatile("s_waitcnt lgkmcnt(0)" ::: "memory");
        __builtin_amdgcn_s_barrier();

        // compose S_in = S_run ∘ T_0 ∘ ... ∘ T_{wid-1}
        float p = Sp[sl][lane], q = Sq[sl][lane], o = So[sl][lane];
        for (int j = 0; j < wid; ++j) {       // wave-uniform trip count
            const float Oj = To[sl][j][lane];
            const float a  = o + wCH;
            const float d  = a - Oj;
            const float e  = __builtin_amdgcn_exp2f(-fabsf(d));
            const float sA = d >= 0.f ? 1.f : e;
            const float sB = d >= 0.f ? e : 1.f;
            p = fmaf(sA, p, sB * Tp[sl][j][lane]);
            q = fmaf(sA, q, sB * Tq[sl][j][lane]);
            o = fmaxf(a, Oj);
        }

        // new running state (compose result + own totals)
        if (wid == WAVES - 1) {
            const float Ot = fmaf((float)(CHUNK - 1), wc, M);
            const float a  = o + wCH;
            const float d  = a - Ot;
            const float e  = __builtin_amdgcn_exp2f(-fabsf(d));
            const float sA = d >= 0.f ? 1.f : e;
            const float sB = d >= 0.f ? e : 1.f;
            Sp[1 - sl][lane] = fmaf(sA, p, sB * Pt);
            Sq[1 - sl][lane] = fmaf(sA, q, sB * Qt);
            So[1 - sl][lane] = fmaxf(a, Ot);
        }

        // y loop: exact per-step normalizer (max3); stage y into the
        // CONSUMED lk rows of this slot (intra-wave only)
#pragma unroll
        for (int j = 0; j < CHUNK; ++j) {
            const float g   = fmaf((float)j, wc, o);
            const float no  = fmaxf(fmaxf(g, hh[j]), uk[j]);   // v_max3
            const float ea  = __builtin_amdgcn_exp2f(g - no);
            const float eb  = __builtin_amdgcn_exp2f(hh[j] - no);
            const float ec  = __builtin_amdgcn_exp2f(uk[j] - no);
            const float num = fmaf(ea, p, fmaf(eb, pP[j], ec * vc[j]));
            const float den = fmaf(ea, q, fmaf(eb, pQ[j], ec));
            lk[sl][wid * CHUNK + j][lane] = __fdividef(num, den);
        }

        // staged y visible to this wave's own readback lanes
        asm volatile("s_waitcnt lgkmcnt(0)" ::: "memory");
        __builtin_amdgcn_sched_barrier(0);

        // wide y out: 2 nontemporal dwordx4 stores (1KB/instr granule)
        const int tb = s * SEG + wid * CHUNK;
#pragma unroll
        for (int g = 0; g < 2; ++g) {
            const f32x4 yv = *reinterpret_cast<const f32x4*>(
                &lk[sl][wid * CHUNK + 4 * g + rl][cl]);
            __builtin_nontemporal_store(yv,
                reinterpret_cast<f32x4*>(ysb + (size_t)(tb + 4 * g) * CDIM));
        }

        // readback ds_reads retired -> safe to let refill DMA overwrite rows
        asm volatile("s_waitcnt lgkmcnt(0)" ::: "memory");
        __builtin_amdgcn_sched_barrier(0);
        if (s + 2 < NSEG) issue_seg(s + 2);
    }
}

extern "C" void kernel_launch(void* const* d_in, const int* in_sizes, int n_in,
                              void* d_out, int out_size, void* d_ws, size_t ws_size,
                              hipStream_t stream) {
    // inputs: 0=B, 1=T, 2=C (scalars), 3=w[C], 4=u[C], 5=k[B*T*C], 6=v[B*T*C]
    const float* w = (const float*)d_in[3];
    const float* u = (const float*)d_in[4];
    const float* k = (const float*)d_in[5];
    const float* v = (const float*)d_in[6];
    float* y = (float*)d_out;

    const int B = in_sizes[5] / (T_DIM * CDIM);   // 16

    dim3 grid(CDIM / 64, B);
    dim3 block(WAVES * 64);
    wkv_fwd_kernel<<<grid, block, 0, stream>>>(w, u, k, v, y);
}